// Round 2
// baseline (218.839 us; speedup 1.0000x reference)
//
#include <hip/hip_runtime.h>
#include <hip/hip_bf16.h>
#include <stdint.h>

typedef __attribute__((ext_vector_type(8))) short short8;
typedef __attribute__((ext_vector_type(4))) float f32x4;

#define N_SLOTS 65536
#define D_FEAT  64
#define BATCH   2048
#define BM      64               // batch rows per block
#define BK      64               // k per iteration
#define NC      32               // k-chunks (grid.y)
#define KCHUNK  (N_SLOTS / NC)   // 2048
#define NITER   (KCHUNK / BK)    // 32

// float -> bf16 bits, round-to-nearest-even
__device__ __forceinline__ unsigned short f2bf(float f) {
    unsigned int u = __builtin_bit_cast(unsigned int, f);
    u += 0x7fffu + ((u >> 16) & 1u);
    return (unsigned short)(u >> 16);
}

// Kernel 0: M [N_SLOTS][64] f32 -> MT [64][N_SLOTS] bf16 (transpose + convert, runs once)
__global__ __launch_bounds__(256) void convert_mt(const float* __restrict__ M,
                                                  unsigned short* __restrict__ MT) {
    __shared__ unsigned short s[64][72];   // +8 pad to break bank aliasing
    const int t  = threadIdx.x;
    const int k0 = blockIdx.x * 64;
    #pragma unroll
    for (int j = 0; j < 4; ++j) {
        const int r = j * 16 + (t >> 4);
        const int c = (t & 15) * 4;
        const float4 v = *reinterpret_cast<const float4*>(M + (size_t)(k0 + r) * D_FEAT + c);
        s[r][c + 0] = f2bf(v.x); s[r][c + 1] = f2bf(v.y);
        s[r][c + 2] = f2bf(v.z); s[r][c + 3] = f2bf(v.w);
    }
    __syncthreads();
    #pragma unroll
    for (int j = 0; j < 2; ++j) {
        const int d  = j * 32 + (t >> 3);
        const int kk = (t & 7) * 8;
        short8 v;
        #pragma unroll
        for (int e = 0; e < 8; ++e) v[e] = (short)s[kk + e][d];
        *reinterpret_cast<short8*>(MT + (size_t)d * N_SLOTS + k0 + kk) = v;
    }
}

// Main: fused exp(W)@M with zero LDS / zero barriers.
// A-frag: exp of W loaded in-register; B-frag: direct short8 load from MT (L2-hot).
// A and B use the SAME (laneGroup,e)->k map, so any HW k-permutation cancels.
__global__ __launch_bounds__(256, 4) void reading_main(
    const unsigned short* __restrict__ MT,  // [64][N_SLOTS] bf16
    const float* __restrict__ W,            // [BATCH][N_SLOTS] f32
    float* __restrict__ out,                // [BATCH][64] numerator accum (pre-zeroed)
    float* __restrict__ lrow)               // [BATCH] denominator accum (pre-zeroed)
{
    const int t   = threadIdx.x;
    const int ln  = t & 63;
    const int wv  = t >> 6;      // wave 0..3 -> batch rows 16*wv..16*wv+15
    const int r   = ln & 15;     // A row within 16 / B output column (d within tile)
    const int g   = ln >> 4;     // k lane-group 0..3
    const int bm0 = blockIdx.x * BM;
    const int kc0 = blockIdx.y * KCHUNK;

    const size_t wbase = (size_t)(bm0 + 16 * wv + r) * N_SLOTS;

    float lsum = 0.f;
    f32x4 acc[4];
    #pragma unroll
    for (int td = 0; td < 4; ++td) acc[td] = f32x4{0.f, 0.f, 0.f, 0.f};

    #pragma unroll 2
    for (int it = 0; it < NITER; ++it) {
        const int kbase = kc0 + it * BK;
        #pragma unroll
        for (int ks = 0; ks < 2; ++ks) {
            const int ka = kbase + ks * 32 + g * 8;   // this lane's 8-float k window

            const float4 w0 = *reinterpret_cast<const float4*>(W + wbase + ka);
            const float4 w1 = *reinterpret_cast<const float4*>(W + wbase + ka + 4);

            const float e0 = __expf(w0.x), e1 = __expf(w0.y);
            const float e2 = __expf(w0.z), e3 = __expf(w0.w);
            const float e4 = __expf(w1.x), e5 = __expf(w1.y);
            const float e6 = __expf(w1.z), e7 = __expf(w1.w);
            lsum += ((e0 + e1) + (e2 + e3)) + ((e4 + e5) + (e6 + e7));

            short8 a;
            a[0] = (short)f2bf(e0); a[1] = (short)f2bf(e1);
            a[2] = (short)f2bf(e2); a[3] = (short)f2bf(e3);
            a[4] = (short)f2bf(e4); a[5] = (short)f2bf(e5);
            a[6] = (short)f2bf(e6); a[7] = (short)f2bf(e7);

            #pragma unroll
            for (int td = 0; td < 4; ++td) {
                const short8 b = *reinterpret_cast<const short8*>(
                    MT + (size_t)(16 * td + r) * N_SLOTS + ka);
                acc[td] = __builtin_amdgcn_mfma_f32_16x16x32_bf16(a, b, acc[td], 0, 0, 0);
            }
        }
    }

    // numerator tile: C/D map col=lane&15, row=(lane>>4)*4+q  (verified in R1)
    #pragma unroll
    for (int td = 0; td < 4; ++td) {
        #pragma unroll
        for (int q = 0; q < 4; ++q) {
            atomicAdd(&out[(size_t)(bm0 + 16 * wv + g * 4 + q) * D_FEAT + 16 * td + r],
                      acc[td][q]);
        }
    }

    // denominator: lanes {r, r+16, r+32, r+48} hold partial sums for batch row r
    float s = lsum;
    s += __shfl_xor(s, 16, 64);
    s += __shfl_xor(s, 32, 64);
    if (ln < 16) atomicAdd(&lrow[bm0 + 16 * wv + ln], s);
}

__global__ __launch_bounds__(256) void reading_finalize(
    float* __restrict__ out, const float* __restrict__ lrow)
{
    const int i = blockIdx.x * 256 + threadIdx.x;   // BATCH*D_FEAT total
    out[i] = out[i] / lrow[i >> 6];
}

extern "C" void kernel_launch(void* const* d_in, const int* in_sizes, int n_in,
                              void* d_out, int out_size, void* d_ws, size_t ws_size,
                              hipStream_t stream) {
    const float* M = (const float*)d_in[0];   // memory [65536][64]
    const float* W = (const float*)d_in[1];   // weight [2048][65536]
    float* out  = (float*)d_out;
    float* lrow = (float*)d_ws;                                    // 8 KB
    unsigned short* MT = (unsigned short*)((char*)d_ws + 65536);   // 8 MB bf16 M^T

    hipMemsetAsync(d_out, 0, (size_t)BATCH * D_FEAT * sizeof(float), stream);
    hipMemsetAsync(d_ws,  0, (size_t)BATCH * sizeof(float), stream);

    convert_mt<<<N_SLOTS / 64, 256, 0, stream>>>(M, MT);

    dim3 grid(BATCH / BM, NC);
    reading_main<<<grid, 256, 0, stream>>>(MT, W, out, lrow);
    reading_finalize<<<(BATCH * D_FEAT) / 256, 256, 0, stream>>>(out, lrow);
}

// Round 3
// 148.827 us; speedup vs baseline: 1.4704x; 1.4704x over previous
//
#include <hip/hip_runtime.h>
#include <hip/hip_bf16.h>
#include <stdint.h>

typedef __attribute__((ext_vector_type(8))) short short8;
typedef __attribute__((ext_vector_type(4))) float f32x4;

#define N_SLOTS 65536
#define D_FEAT  64
#define BATCH   2048
#define BM      64               // batch rows per block
#define BK      64               // k per iteration
#define NC      32               // k-chunks (grid y dimension, folded into 1D)
#define KCHUNK  (N_SLOTS / NC)   // 2048
#define NITER   (KCHUNK / BK)    // 32

// float -> bf16 bits, round-to-nearest-even
__device__ __forceinline__ unsigned short f2bf(float f) {
    unsigned int u = __builtin_bit_cast(unsigned int, f);
    u += 0x7fffu + ((u >> 16) & 1u);
    return (unsigned short)(u >> 16);
}

// Kernel 0: M [N_SLOTS][64] f32 -> MT [64][N_SLOTS] bf16 (runs once, ~4 us)
__global__ __launch_bounds__(256) void convert_mt(const float* __restrict__ M,
                                                  unsigned short* __restrict__ MT) {
    __shared__ unsigned short s[64][72];   // +8 pad breaks bank aliasing
    const int t  = threadIdx.x;
    const int k0 = blockIdx.x * 64;
    #pragma unroll
    for (int j = 0; j < 4; ++j) {
        const int r = j * 16 + (t >> 4);
        const int c = (t & 15) * 4;
        const float4 v = *reinterpret_cast<const float4*>(M + (size_t)(k0 + r) * D_FEAT + c);
        s[r][c + 0] = f2bf(v.x); s[r][c + 1] = f2bf(v.y);
        s[r][c + 2] = f2bf(v.z); s[r][c + 3] = f2bf(v.w);
    }
    __syncthreads();
    #pragma unroll
    for (int j = 0; j < 2; ++j) {
        const int d  = j * 32 + (t >> 3);
        const int kk = (t & 7) * 8;
        short8 v;
        #pragma unroll
        for (int e = 0; e < 8; ++e) v[e] = (short)s[kk + e][d];
        *reinterpret_cast<short8*>(MT + (size_t)d * N_SLOTS + k0 + kk) = v;
    }
}

// Main: A (exp of W) lives in registers; B (MT slice) double-buffered in LDS.
// Depth-1 pipeline: issue it+1 loads, compute it, stage-write it+1, barrier.
__global__ __launch_bounds__(256) void reading_main(
    const unsigned short* __restrict__ MT,  // [64][N_SLOTS] bf16
    const float* __restrict__ W,            // [BATCH][N_SLOTS] f32
    float* __restrict__ out,                // [BATCH][64] numerator accum (pre-zeroed)
    float* __restrict__ lrow)               // [BATCH] denominator accum (pre-zeroed)
{
    __shared__ __align__(16) unsigned short sB[2][D_FEAT * BK];   // 2 x 8 KB

    const int t  = threadIdx.x;
    const int ln = t & 63;
    const int wv = t >> 6;      // wave 0..3 -> batch rows 16*wv..16*wv+15
    const int r  = ln & 15;     // A row within 16 / B LDS-row low bits
    const int g  = ln >> 4;     // k lane-group 0..3

    // bijective XCD swizzle: XCD (bid&7) owns 4 contiguous k-chunks -> MT slice L2-resident
    const int bid = blockIdx.x;                     // 0..1023
    const int wg  = ((bid & 7) << 7) | (bid >> 3);  // bijective
    const int by  = wg >> 5;                        // k-chunk 0..31
    const int bx  = wg & 31;                        // batch tile 0..31
    const int bm0 = bx * BM;
    const int kc0 = by * KCHUNK;

    const size_t wbase = (size_t)(bm0 + 16 * wv + r) * N_SLOTS + kc0;

    // B staging map: chunk i in {0,1}: d = wv*16 + i*8 + (ln>>3), j = ln&7
    // linear coalesced global read; XOR-swizzled LDS write (byte ^= ((d&7)<<4))
    const int sd0 = wv * 16 + (ln >> 3);
    const int sj  = ln & 7;
    const size_t msrc0 = (size_t)sd0 * N_SLOTS + kc0 + sj * 8;        // ushort offset
    const int    ldst0 = sd0 * BK + ((sj ^ (sd0 & 7)) * 8);
    const int sd1 = sd0 + 8;
    const size_t msrc1 = (size_t)sd1 * N_SLOTS + kc0 + sj * 8;
    const int    ldst1 = sd1 * BK + ((sj ^ (sd1 & 7)) * 8);

    // B fragment read bases (ushort idx within buffer; + td*1024 immediate per tile)
    const int rx  = r & 7;
    const int rb0 = r * BK + (((0 * 4 + g) ^ rx) * 8);   // ks=0
    const int rb1 = r * BK + (((1 * 4 + g) ^ rx) * 8);   // ks=1

    float lsum = 0.f;
    f32x4 acc[4];
    #pragma unroll
    for (int td = 0; td < 4; ++td) acc[td] = f32x4{0.f, 0.f, 0.f, 0.f};

    // ---- prologue: stage B(0), issue W(0)
    {
        const short8 p0 = *reinterpret_cast<const short8*>(MT + msrc0);
        const short8 p1 = *reinterpret_cast<const short8*>(MT + msrc1);
        *reinterpret_cast<short8*>(&sB[0][ldst0]) = p0;
        *reinterpret_cast<short8*>(&sB[0][ldst1]) = p1;
    }
    float4 wa0 = *reinterpret_cast<const float4*>(W + wbase + g * 8);
    float4 wa1 = *reinterpret_cast<const float4*>(W + wbase + g * 8 + 4);
    float4 wb0 = *reinterpret_cast<const float4*>(W + wbase + 32 + g * 8);
    float4 wb1 = *reinterpret_cast<const float4*>(W + wbase + 32 + g * 8 + 4);
    __syncthreads();

    #pragma unroll 2
    for (int it = 0; it < NITER; ++it) {
        const bool more = (it + 1 < NITER);
        const int  nk   = (it + 1) * BK;

        // ---- issue next-iter loads (overlap this iter's compute)
        short8 nb0, nb1;
        float4 xa0, xa1, xb0, xb1;
        if (more) {
            nb0 = *reinterpret_cast<const short8*>(MT + msrc0 + nk);
            nb1 = *reinterpret_cast<const short8*>(MT + msrc1 + nk);
            xa0 = *reinterpret_cast<const float4*>(W + wbase + nk + g * 8);
            xa1 = *reinterpret_cast<const float4*>(W + wbase + nk + g * 8 + 4);
            xb0 = *reinterpret_cast<const float4*>(W + wbase + nk + 32 + g * 8);
            xb1 = *reinterpret_cast<const float4*>(W + wbase + nk + 32 + g * 8 + 4);
        }

        // ---- compute(it): exp -> A frags in registers
        const float e0 = __expf(wa0.x), e1 = __expf(wa0.y);
        const float e2 = __expf(wa0.z), e3 = __expf(wa0.w);
        const float e4 = __expf(wa1.x), e5 = __expf(wa1.y);
        const float e6 = __expf(wa1.z), e7 = __expf(wa1.w);
        const float f0 = __expf(wb0.x), f1 = __expf(wb0.y);
        const float f2 = __expf(wb0.z), f3 = __expf(wb0.w);
        const float f4 = __expf(wb1.x), f5 = __expf(wb1.y);
        const float f6 = __expf(wb1.z), f7 = __expf(wb1.w);
        lsum += (((e0 + e1) + (e2 + e3)) + ((e4 + e5) + (e6 + e7)))
              + (((f0 + f1) + (f2 + f3)) + ((f4 + f5) + (f6 + f7)));

        short8 a0, a1;
        a0[0] = (short)f2bf(e0); a0[1] = (short)f2bf(e1);
        a0[2] = (short)f2bf(e2); a0[3] = (short)f2bf(e3);
        a0[4] = (short)f2bf(e4); a0[5] = (short)f2bf(e5);
        a0[6] = (short)f2bf(e6); a0[7] = (short)f2bf(e7);
        a1[0] = (short)f2bf(f0); a1[1] = (short)f2bf(f1);
        a1[2] = (short)f2bf(f2); a1[3] = (short)f2bf(f3);
        a1[4] = (short)f2bf(f4); a1[5] = (short)f2bf(f5);
        a1[6] = (short)f2bf(f6); a1[7] = (short)f2bf(f7);

        const unsigned short* buf = sB[it & 1];
        #pragma unroll
        for (int td = 0; td < 4; ++td) {
            const short8 q0 = *reinterpret_cast<const short8*>(buf + td * 16 * BK + rb0);
            acc[td] = __builtin_amdgcn_mfma_f32_16x16x32_bf16(a0, q0, acc[td], 0, 0, 0);
            const short8 q1 = *reinterpret_cast<const short8*>(buf + td * 16 * BK + rb1);
            acc[td] = __builtin_amdgcn_mfma_f32_16x16x32_bf16(a1, q1, acc[td], 0, 0, 0);
        }

        // ---- stage-write next B tile (waits only on nb0/nb1)
        if (more) {
            unsigned short* nbuf = sB[(it + 1) & 1];
            *reinterpret_cast<short8*>(nbuf + ldst0) = nb0;
            *reinterpret_cast<short8*>(nbuf + ldst1) = nb1;
        }
        __syncthreads();

        if (more) { wa0 = xa0; wa1 = xa1; wb0 = xb0; wb1 = xb1; }
    }

    // numerator tile: C/D map col=lane&15, row=(lane>>4)*4+q (verified R1)
    #pragma unroll
    for (int td = 0; td < 4; ++td) {
        #pragma unroll
        for (int q = 0; q < 4; ++q) {
            atomicAdd(&out[(size_t)(bm0 + 16 * wv + g * 4 + q) * D_FEAT + 16 * td + r],
                      acc[td][q]);
        }
    }

    // denominator: lanes {r, r+16, r+32, r+48} hold partials for batch row r
    float s = lsum;
    s += __shfl_xor(s, 16, 64);
    s += __shfl_xor(s, 32, 64);
    if (ln < 16) atomicAdd(&lrow[bm0 + 16 * wv + ln], s);
}

__global__ __launch_bounds__(256) void reading_finalize(
    float* __restrict__ out, const float* __restrict__ lrow)
{
    const int i = blockIdx.x * 256 + threadIdx.x;   // BATCH*D_FEAT total
    out[i] = out[i] / lrow[i >> 6];
}

extern "C" void kernel_launch(void* const* d_in, const int* in_sizes, int n_in,
                              void* d_out, int out_size, void* d_ws, size_t ws_size,
                              hipStream_t stream) {
    const float* M = (const float*)d_in[0];   // memory [65536][64]
    const float* W = (const float*)d_in[1];   // weight [2048][65536]
    float* out  = (float*)d_out;
    float* lrow = (float*)d_ws;                                    // 8 KB
    unsigned short* MT = (unsigned short*)((char*)d_ws + 65536);   // 8 MB bf16 M^T

    hipMemsetAsync(d_out, 0, (size_t)BATCH * D_FEAT * sizeof(float), stream);
    hipMemsetAsync(d_ws,  0, (size_t)BATCH * sizeof(float), stream);

    convert_mt<<<N_SLOTS / 64, 256, 0, stream>>>(M, MT);

    reading_main<<<(BATCH / BM) * NC, 256, 0, stream>>>(MT, W, out, lrow);
    reading_finalize<<<(BATCH * D_FEAT) / 256, 256, 0, stream>>>(out, lrow);
}

// Round 4
// 140.495 us; speedup vs baseline: 1.5576x; 1.0593x over previous
//
#include <hip/hip_runtime.h>
#include <hip/hip_bf16.h>
#include <stdint.h>

typedef __attribute__((ext_vector_type(8))) short short8;
typedef __attribute__((ext_vector_type(4))) float f32x4;

#define N_SLOTS 65536
#define D_FEAT  64
#define BATCH   2048
#define BM      64               // batch rows per block
#define BK      128              // k per iteration (512 B per W row -> DRAM-friendly)
#define NC      32               // k-chunks
#define KCHUNK  (N_SLOTS / NC)   // 2048
#define NITER   (KCHUNK / BK)    // 16

// float -> bf16 bits, round-to-nearest-even
__device__ __forceinline__ unsigned short f2bf(float f) {
    unsigned int u = __builtin_bit_cast(unsigned int, f);
    u += 0x7fffu + ((u >> 16) & 1u);
    return (unsigned short)(u >> 16);
}
__device__ __forceinline__ unsigned int pk2(float a, float b) {
    return (unsigned int)f2bf(a) | ((unsigned int)f2bf(b) << 16);
}

// Kernel 0: M [N_SLOTS][64] f32 -> MT [64][N_SLOTS] bf16 (runs once, ~4 us)
__global__ __launch_bounds__(256) void convert_mt(const float* __restrict__ M,
                                                  unsigned short* __restrict__ MT) {
    __shared__ unsigned short s[64][72];
    const int t  = threadIdx.x;
    const int k0 = blockIdx.x * 64;
    #pragma unroll
    for (int j = 0; j < 4; ++j) {
        const int r = j * 16 + (t >> 4);
        const int c = (t & 15) * 4;
        const float4 v = *reinterpret_cast<const float4*>(M + (size_t)(k0 + r) * D_FEAT + c);
        s[r][c + 0] = f2bf(v.x); s[r][c + 1] = f2bf(v.y);
        s[r][c + 2] = f2bf(v.z); s[r][c + 3] = f2bf(v.w);
    }
    __syncthreads();
    #pragma unroll
    for (int j = 0; j < 2; ++j) {
        const int d  = j * 32 + (t >> 3);
        const int kk = (t & 7) * 8;
        short8 v;
        #pragma unroll
        for (int e = 0; e < 8; ++e) v[e] = (short)s[kk + e][d];
        *reinterpret_cast<short8*>(MT + (size_t)d * N_SLOTS + k0 + kk) = v;
    }
}

// Main: A(exp W) and B(MT) single-buffered in LDS; W read in 512B row-contiguous
// chunks; registers prefetch it+1 across raw barriers (no vmcnt(0) drain).
__global__ __launch_bounds__(256) void reading_main(
    const unsigned short* __restrict__ MT,  // [64][N_SLOTS] bf16
    const float* __restrict__ W,            // [BATCH][N_SLOTS] f32
    float* __restrict__ out_p,              // [NC][BATCH][64] partials
    float* __restrict__ lrow)               // [BATCH] denominator accum (pre-zeroed)
{
    __shared__ __align__(16) unsigned short sA[BM * BK];      // 16 KB
    __shared__ __align__(16) unsigned short sB[D_FEAT * BK];  // 16 KB

    const int t  = threadIdx.x;
    const int ln = t & 63;
    const int wv = t >> 6;      // wave 0..3 -> batch rows 16*wv..16*wv+15
    const int r  = ln & 15;
    const int g  = ln >> 4;     // k lane-group 0..3
    const int hi = ln >> 5;     // 0/1 half-wave

    // bijective XCD swizzle: XCD (bid&7) owns k-chunks 4x..4x+3 -> MT slice (1MB) L2-hot
    const int bid = blockIdx.x;
    const int wg  = ((bid & 7) << 7) | (bid >> 3);
    const int by  = wg >> 5;
    const int bx  = wg & 31;
    const int bm0 = bx * BM;
    const int kc0 = by * KCHUNK;

    // A staging: instr j loads rows wv*16 + j*2 + hi; 32 lanes x float4 = 512B/row
    const int    kq    = (ln & 31) * 4;   // k offset (elements)
    const size_t wbase = (size_t)(bm0 + wv * 16 + hi) * N_SLOTS + kc0 + kq;
    // B staging: instr i loads rows d = wv*16 + i*4 + (ln>>4); 16 lanes x short8 = 256B/row
    const int    sd    = wv * 16 + (ln >> 4);
    const int    kb    = (ln & 15) * 8;
    const size_t mbase = (size_t)sd * N_SLOTS + kc0 + kb;

    float lsum[8];
    #pragma unroll
    for (int j = 0; j < 8; ++j) lsum[j] = 0.f;
    f32x4 acc[4];
    #pragma unroll
    for (int td = 0; td < 4; ++td) acc[td] = f32x4{0.f, 0.f, 0.f, 0.f};

    float4 pw[8];
    short8 pm[4];

    #define ISSUE(itn) do { \
        _Pragma("unroll") for (int j = 0; j < 8; ++j) \
            pw[j] = *reinterpret_cast<const float4*>(W + wbase + (size_t)j * 2 * N_SLOTS + (size_t)(itn) * BK); \
        _Pragma("unroll") for (int i = 0; i < 4; ++i) \
            pm[i] = *reinterpret_cast<const short8*>(MT + mbase + (size_t)i * 4 * N_SLOTS + (size_t)(itn) * BK); \
    } while (0)

    #define WRITE_STAGE() do { \
        _Pragma("unroll") for (int j = 0; j < 8; ++j) { \
            const float e0 = __expf(pw[j].x), e1 = __expf(pw[j].y); \
            const float e2 = __expf(pw[j].z), e3 = __expf(pw[j].w); \
            lsum[j] += (e0 + e1) + (e2 + e3); \
            const unsigned long long pk = (unsigned long long)pk2(e0, e1) \
                                        | ((unsigned long long)pk2(e2, e3) << 32); \
            const int rj = wv * 16 + j * 2 + hi; \
            *reinterpret_cast<unsigned long long*>(&sA[rj * BK + (kq ^ ((rj & 7) * 8))]) = pk; \
        } \
        _Pragma("unroll") for (int i = 0; i < 4; ++i) { \
            const int d = sd + i * 4; \
            *reinterpret_cast<short8*>(&sB[d * BK + (kb ^ ((d & 7) * 8))]) = pm[i]; \
        } \
    } while (0)

    #define COMPUTE() do { \
        _Pragma("unroll") for (int ks = 0; ks < 4; ++ks) { \
            const int ko = (ks * 32 + g * 8) ^ ((r & 7) * 8); \
            const short8 a = *reinterpret_cast<const short8*>(&sA[(16 * wv + r) * BK + ko]); \
            _Pragma("unroll") for (int td = 0; td < 4; ++td) { \
                const short8 b = *reinterpret_cast<const short8*>(&sB[(16 * td + r) * BK + ko]); \
                acc[td] = __builtin_amdgcn_mfma_f32_16x16x32_bf16(a, b, acc[td], 0, 0, 0); \
            } \
        } \
    } while (0)

    #define BAR_PLAIN() do { \
        __builtin_amdgcn_sched_barrier(0); \
        __builtin_amdgcn_s_barrier(); \
        __builtin_amdgcn_sched_barrier(0); \
    } while (0)

    #define BAR_LGKM() do { \
        __builtin_amdgcn_sched_barrier(0); \
        asm volatile("s_waitcnt lgkmcnt(0)" ::: "memory"); \
        __builtin_amdgcn_s_barrier(); \
        __builtin_amdgcn_sched_barrier(0); \
    } while (0)

    // prologue: stage tile 0
    ISSUE(0);
    WRITE_STAGE();
    BAR_LGKM();

    #pragma unroll 1
    for (int it = 0; it < NITER; ++it) {
        const bool more = (it + 1 < NITER);
        if (more) { ISSUE(it + 1); __builtin_amdgcn_sched_barrier(0); }
        COMPUTE();          // ds_reads consumed in-order by MFMA before barrier
        if (more) {
            BAR_PLAIN();    // all waves done reading sA/sB (no vmcnt drain: W stays in flight)
            WRITE_STAGE();  // compiler waits counted vmcnt for pw/pm here
            BAR_LGKM();     // writes visible to all waves
        }
    }

    // numerator tile -> partials (plain stores; C/D map col=r, row=g*4+q, verified R1)
    {
        float* op = out_p + (size_t)by * (BATCH * D_FEAT) + (size_t)bm0 * D_FEAT;
        #pragma unroll
        for (int td = 0; td < 4; ++td) {
            #pragma unroll
            for (int q = 0; q < 4; ++q) {
                op[(16 * wv + g * 4 + q) * D_FEAT + 16 * td + r] = acc[td][q];
            }
        }
    }

    // denominator: lane sums -> per-row totals (reduce within 32-lane halves)
    #pragma unroll
    for (int j = 0; j < 8; ++j) {
        float s = lsum[j];
        s += __shfl_xor(s, 1, 64);
        s += __shfl_xor(s, 2, 64);
        s += __shfl_xor(s, 4, 64);
        s += __shfl_xor(s, 8, 64);
        s += __shfl_xor(s, 16, 64);
        if ((ln & 31) == 0)
            atomicAdd(&lrow[bm0 + wv * 16 + j * 2 + hi], s);
    }
}

__global__ __launch_bounds__(256) void reading_finalize(
    const float* __restrict__ out_p, const float* __restrict__ lrow,
    float* __restrict__ out)
{
    const int i = blockIdx.x * 256 + threadIdx.x;   // BATCH*D_FEAT total
    float s = 0.f;
    #pragma unroll
    for (int c = 0; c < NC; ++c)
        s += out_p[(size_t)c * (BATCH * D_FEAT) + i];
    out[i] = s / lrow[i >> 6];
}

extern "C" void kernel_launch(void* const* d_in, const int* in_sizes, int n_in,
                              void* d_out, int out_size, void* d_ws, size_t ws_size,
                              hipStream_t stream) {
    const float* M = (const float*)d_in[0];   // memory [65536][64]
    const float* W = (const float*)d_in[1];   // weight [2048][65536]
    float* out = (float*)d_out;

    float*          lrow  = (float*)d_ws;                                  // 8 KB
    unsigned short* MT    = (unsigned short*)((char*)d_ws + (1 << 16));    // 8 MB
    float*          out_p = (float*)((char*)d_ws + (1 << 16) + (1 << 23)); // 16 MB

    hipMemsetAsync(d_ws, 0, (size_t)BATCH * sizeof(float), stream);

    convert_mt<<<N_SLOTS / 64, 256, 0, stream>>>(M, MT);
    reading_main<<<(BATCH / BM) * NC, 256, 0, stream>>>(MT, W, out_p, lrow);
    reading_finalize<<<(BATCH * D_FEAT) / 256, 256, 0, stream>>>(out_p, lrow, out);
}

// Round 5
// 128.397 us; speedup vs baseline: 1.7044x; 1.0942x over previous
//
#include <hip/hip_runtime.h>
#include <hip/hip_bf16.h>
#include <stdint.h>

typedef __attribute__((ext_vector_type(8))) short short8;
typedef __attribute__((ext_vector_type(4))) float f32x4;

#define N_SLOTS 65536
#define D_FEAT  64
#define BATCH   2048
#define BM      64               // batch rows per block
#define BK      128              // k per tile (512 B per W row)
#define NC      32               // k-chunk slots (by)
#define NITER   16               // tiles per block

// float -> bf16 bits, round-to-nearest-even
__device__ __forceinline__ unsigned short f2bf(float f) {
    unsigned int u = __builtin_bit_cast(unsigned int, f);
    u += 0x7fffu + ((u >> 16) & 1u);
    return (unsigned short)(u >> 16);
}
__device__ __forceinline__ unsigned int pk2(float a, float b) {
    return (unsigned int)f2bf(a) | ((unsigned int)f2bf(b) << 16);
}

// Kernel 0: M [N_SLOTS][64] f32 -> MT [64][N_SLOTS] bf16 (runs once, ~4 us)
__global__ __launch_bounds__(256) void convert_mt(const float* __restrict__ M,
                                                  unsigned short* __restrict__ MT) {
    __shared__ unsigned short s[64][72];
    const int t  = threadIdx.x;
    const int k0 = blockIdx.x * 64;
    #pragma unroll
    for (int j = 0; j < 4; ++j) {
        const int r = j * 16 + (t >> 4);
        const int c = (t & 15) * 4;
        const float4 v = *reinterpret_cast<const float4*>(M + (size_t)(k0 + r) * D_FEAT + c);
        s[r][c + 0] = f2bf(v.x); s[r][c + 1] = f2bf(v.y);
        s[r][c + 2] = f2bf(v.z); s[r][c + 3] = f2bf(v.w);
    }
    __syncthreads();
    #pragma unroll
    for (int j = 0; j < 2; ++j) {
        const int d  = j * 32 + (t >> 3);
        const int kk = (t & 7) * 8;
        short8 v;
        #pragma unroll
        for (int e = 0; e < 8; ++e) v[e] = (short)s[kk + e][d];
        *reinterpret_cast<short8*>(MT + (size_t)d * N_SLOTS + k0 + kk) = v;
    }
}

// Main: A(exp W) and B(MT) single-buffered in LDS; tile s of block (bx,by) reads
// columns (((s+bx)&15)*NC + by)*BK  -> phase-rotated, globally spread, 16KB runs.
__global__ __launch_bounds__(256) void reading_main(
    const unsigned short* __restrict__ MT,  // [64][N_SLOTS] bf16
    const float* __restrict__ W,            // [BATCH][N_SLOTS] f32
    float* __restrict__ out_p,              // [NC][BATCH][64] partials
    float* __restrict__ lrow)               // [BATCH] denominator accum (pre-zeroed)
{
    __shared__ __align__(16) unsigned short sA[BM * BK];      // 16 KB
    __shared__ __align__(16) unsigned short sB[D_FEAT * BK];  // 16 KB

    const int t  = threadIdx.x;
    const int ln = t & 63;
    const int wv = t >> 6;      // wave 0..3 -> batch rows 16*wv..16*wv+15
    const int r  = ln & 15;
    const int g  = ln >> 4;     // k lane-group 0..3
    const int hi = ln >> 5;     // 0/1 half-wave

    // bijective XCD swizzle: XCD (bid&7) keeps a fixed by-congruence class -> L2-local MT
    const int bid = blockIdx.x;
    const int wg  = ((bid & 7) << 7) | (bid >> 3);
    const int by  = wg >> 5;    // 0..31
    const int bx  = wg & 31;    // 0..31
    const int bm0 = bx * BM;

    // A staging: instr j loads rows wv*16 + j*2 + hi; 32 lanes x float4 = 512B/row
    const int    kq    = (ln & 31) * 4;
    const size_t wbase = (size_t)(bm0 + wv * 16 + hi) * N_SLOTS + kq;
    // B staging: instr i loads rows d = wv*16 + i*4 + (ln>>4); 16 lanes x short8
    const int    sd    = wv * 16 + (ln >> 4);
    const int    kb    = (ln & 15) * 8;
    const size_t mbase = (size_t)sd * N_SLOTS + kb;

    // column element-offset of tile s (phase-rotated interleaved tiling)
    #define COLOF(s) ((size_t)(((((s) + bx) & (NITER - 1)) * NC + by) * BK))

    float lsum[8];
    #pragma unroll
    for (int j = 0; j < 8; ++j) lsum[j] = 0.f;
    f32x4 acc[4];
    #pragma unroll
    for (int td = 0; td < 4; ++td) acc[td] = f32x4{0.f, 0.f, 0.f, 0.f};

    float4 pw[8];
    short8 pm[4];

    #define ISSUE(co) do { \
        _Pragma("unroll") for (int j = 0; j < 8; ++j) \
            pw[j] = *reinterpret_cast<const float4*>(W + wbase + (size_t)j * 2 * N_SLOTS + (co)); \
        _Pragma("unroll") for (int i = 0; i < 4; ++i) \
            pm[i] = *reinterpret_cast<const short8*>(MT + mbase + (size_t)i * 4 * N_SLOTS + (co)); \
    } while (0)

    #define WRITE_STAGE() do { \
        _Pragma("unroll") for (int j = 0; j < 8; ++j) { \
            const float e0 = __expf(pw[j].x), e1 = __expf(pw[j].y); \
            const float e2 = __expf(pw[j].z), e3 = __expf(pw[j].w); \
            lsum[j] += (e0 + e1) + (e2 + e3); \
            const unsigned long long pk = (unsigned long long)pk2(e0, e1) \
                                        | ((unsigned long long)pk2(e2, e3) << 32); \
            const int rj = wv * 16 + j * 2 + hi; \
            *reinterpret_cast<unsigned long long*>(&sA[rj * BK + (kq ^ ((rj & 7) * 8))]) = pk; \
        } \
        _Pragma("unroll") for (int i = 0; i < 4; ++i) { \
            const int d = sd + i * 4; \
            *reinterpret_cast<short8*>(&sB[d * BK + (kb ^ ((d & 7) * 8))]) = pm[i]; \
        } \
    } while (0)

    #define COMPUTE() do { \
        _Pragma("unroll") for (int ks = 0; ks < 4; ++ks) { \
            const int ko = (ks * 32 + g * 8) ^ ((r & 7) * 8); \
            const short8 a = *reinterpret_cast<const short8*>(&sA[(16 * wv + r) * BK + ko]); \
            _Pragma("unroll") for (int td = 0; td < 4; ++td) { \
                const short8 b = *reinterpret_cast<const short8*>(&sB[(16 * td + r) * BK + ko]); \
                acc[td] = __builtin_amdgcn_mfma_f32_16x16x32_bf16(a, b, acc[td], 0, 0, 0); \
            } \
        } \
    } while (0)

    #define BAR_PLAIN() do { \
        __builtin_amdgcn_sched_barrier(0); \
        __builtin_amdgcn_s_barrier(); \
        __builtin_amdgcn_sched_barrier(0); \
    } while (0)

    #define BAR_LGKM() do { \
        __builtin_amdgcn_sched_barrier(0); \
        asm volatile("s_waitcnt lgkmcnt(0)" ::: "memory"); \
        __builtin_amdgcn_s_barrier(); \
        __builtin_amdgcn_sched_barrier(0); \
    } while (0)

    // prologue: stage tile 0
    ISSUE(COLOF(0));
    WRITE_STAGE();
    BAR_LGKM();

    #pragma unroll 1
    for (int s = 0; s < NITER; ++s) {
        const bool more = (s + 1 < NITER);
        if (more) { ISSUE(COLOF(s + 1)); __builtin_amdgcn_sched_barrier(0); }
        COMPUTE();          // ds_reads consumed by MFMA before barrier
        if (more) {
            BAR_PLAIN();    // all waves done reading sA/sB (W loads stay in flight)
            WRITE_STAGE();  // counted vmcnt waits here
            BAR_LGKM();     // staged writes visible to all waves
        }
    }

    // numerator tile -> partials (C/D map col=r, row=g*4+q, verified R1)
    {
        float* op = out_p + (size_t)by * (BATCH * D_FEAT) + (size_t)bm0 * D_FEAT;
        #pragma unroll
        for (int td = 0; td < 4; ++td) {
            #pragma unroll
            for (int q = 0; q < 4; ++q) {
                op[(16 * wv + g * 4 + q) * D_FEAT + 16 * td + r] = acc[td][q];
            }
        }
    }

    // denominator: reduce within 32-lane halves (rows wv*16 + j*2 + hi)
    #pragma unroll
    for (int j = 0; j < 8; ++j) {
        float s2 = lsum[j];
        s2 += __shfl_xor(s2, 1, 64);
        s2 += __shfl_xor(s2, 2, 64);
        s2 += __shfl_xor(s2, 4, 64);
        s2 += __shfl_xor(s2, 8, 64);
        s2 += __shfl_xor(s2, 16, 64);
        if ((ln & 31) == 0)
            atomicAdd(&lrow[bm0 + wv * 16 + j * 2 + hi], s2);
    }
}

__global__ __launch_bounds__(256) void reading_finalize(
    const float* __restrict__ out_p, const float* __restrict__ lrow,
    float* __restrict__ out)
{
    const int i = blockIdx.x * 256 + threadIdx.x;   // BATCH*D_FEAT total
    float s = 0.f;
    #pragma unroll
    for (int c = 0; c < NC; ++c)
        s += out_p[(size_t)c * (BATCH * D_FEAT) + i];
    out[i] = s / lrow[i >> 6];
}

extern "C" void kernel_launch(void* const* d_in, const int* in_sizes, int n_in,
                              void* d_out, int out_size, void* d_ws, size_t ws_size,
                              hipStream_t stream) {
    const float* M = (const float*)d_in[0];   // memory [65536][64]
    const float* W = (const float*)d_in[1];   // weight [2048][65536]
    float* out = (float*)d_out;

    float*          lrow  = (float*)d_ws;                                  // 8 KB
    unsigned short* MT    = (unsigned short*)((char*)d_ws + (1 << 16));    // 8 MB
    float*          out_p = (float*)((char*)d_ws + (1 << 16) + (1 << 23)); // 16 MB

    hipMemsetAsync(d_ws, 0, (size_t)BATCH * sizeof(float), stream);

    convert_mt<<<N_SLOTS / 64, 256, 0, stream>>>(M, MT);
    reading_main<<<(BATCH / BM) * NC, 256, 0, stream>>>(MT, W, out_p, lrow);
    reading_finalize<<<(BATCH * D_FEAT) / 256, 256, 0, stream>>>(out_p, lrow, out);
}